// Round 1
// baseline (5355.647 us; speedup 1.0000x reference)
//
#include <hip/hip_runtime.h>
#include <hip/hip_bf16.h>

// COO SpMM: out[row[e], :] += values[e] * b[col[e], :], d=128, fp32.
// Baseline: 32-lane group per edge, float4 gather of b-row, 4x atomicAdd scatter.

#define D_FEAT 128

__global__ void spmm_atomic_kernel(const int* __restrict__ rowidx,
                                   const int* __restrict__ colidx,
                                   const float* __restrict__ vals,
                                   const float* __restrict__ b,
                                   float* __restrict__ out,
                                   int nnz) {
    // Each 32-thread group handles one edge; lane f covers features [4f, 4f+4).
    int gtid   = blockIdx.x * blockDim.x + threadIdx.x;
    int group  = gtid >> 5;          // edge slot
    int fid    = gtid & 31;          // float4 index within the 128-wide row
    int ngroup = (gridDim.x * blockDim.x) >> 5;

    for (int e = group; e < nnz; e += ngroup) {
        int   r = rowidx[e];
        int   c = colidx[e];
        float v = vals[e];

        const float4* brow = reinterpret_cast<const float4*>(b + (size_t)c * D_FEAT);
        float4 bv = brow[fid];

        float* orow = out + (size_t)r * D_FEAT + (size_t)fid * 4;
        atomicAdd(orow + 0, v * bv.x);
        atomicAdd(orow + 1, v * bv.y);
        atomicAdd(orow + 2, v * bv.z);
        atomicAdd(orow + 3, v * bv.w);
    }
}

extern "C" void kernel_launch(void* const* d_in, const int* in_sizes, int n_in,
                              void* d_out, int out_size, void* d_ws, size_t ws_size,
                              hipStream_t stream) {
    const int*   indices = (const int*)d_in[0];     // (2, NNZ) int32
    const float* values  = (const float*)d_in[1];   // (NNZ,)
    const float* b       = (const float*)d_in[3];   // (n_rows, 128)
    float*       out     = (float*)d_out;           // (n_rows, 128)

    const int nnz = in_sizes[1];
    const int* rowidx = indices;
    const int* colidx = indices + nnz;

    // d_out is poisoned (0xAA) before timing and never re-poisoned; we must
    // zero it ourselves every call (deterministic: same work each call).
    hipMemsetAsync(d_out, 0, (size_t)out_size * sizeof(float), stream);

    const int block = 256;                 // 8 edge-groups per block
    const int grid  = 8192;                // grid-stride; ~49 edges per group
    spmm_atomic_kernel<<<grid, block, 0, stream>>>(rowidx, colidx, values, b, out, nnz);
}

// Round 2
// 766.332 us; speedup vs baseline: 6.9887x; 6.9887x over previous
//
#include <hip/hip_runtime.h>

// COO SpMM via counting-sort by row, then wave-per-row register accumulation.
// out[r,:] = sum_{e: row[e]==r} val[e] * b[col[e],:]   (d=128, fp32)

#define D_FEAT 128
#define SCAN_THREADS 1024

// K1: per-row edge histogram (int atomics, 100k bins)
__global__ void hist_kernel(const int* __restrict__ rowidx, int* __restrict__ cnt, int nnz) {
    int i = blockIdx.x * blockDim.x + threadIdx.x;
    int stride = gridDim.x * blockDim.x;
    for (int e = i; e < nnz; e += stride)
        atomicAdd(&cnt[rowidx[e]], 1);
}

// K2: single-block in-place exclusive scan: counts -> start offsets
__global__ void scan_kernel(int* __restrict__ cnt, int n) {
    __shared__ int sums[SCAN_THREADS];
    int t = threadIdx.x;
    int chunk = (n + SCAN_THREADS - 1) / SCAN_THREADS;
    int beg = t * chunk;
    int end = min(beg + chunk, n);
    int s = 0;
    for (int i = beg; i < end; ++i) s += cnt[i];
    sums[t] = s;
    __syncthreads();
    // Hillis-Steele inclusive scan over thread sums
    for (int off = 1; off < SCAN_THREADS; off <<= 1) {
        int v = (t >= off) ? sums[t - off] : 0;
        __syncthreads();
        sums[t] += v;
        __syncthreads();
    }
    int run = (t == 0) ? 0 : sums[t - 1];
    for (int i = beg; i < end; ++i) {
        int c = cnt[i];
        cnt[i] = run;   // exclusive start offset
        run += c;
    }
}

// K3: scatter edges into row-sorted order; cursor[] holds start offsets,
// becomes end offsets after this kernel. Pack (col,val) into one float2.
__global__ void scatter_kernel(const int* __restrict__ rowidx, const int* __restrict__ colidx,
                               const float* __restrict__ vals, int* __restrict__ cursor,
                               float2* __restrict__ cv, int nnz) {
    int i = blockIdx.x * blockDim.x + threadIdx.x;
    int stride = gridDim.x * blockDim.x;
    for (int e = i; e < nnz; e += stride) {
        int r = rowidx[e];
        int pos = atomicAdd(&cursor[r], 1);
        cv[pos] = make_float2(__int_as_float(colidx[e]), vals[e]);
    }
}

// K4: one 64-lane wave per output row; lane owns 2 consecutive features.
// rowend[r] = end offset of row r (start = rowend[r-1], row 0 starts at 0).
__global__ void rowmm_kernel(const int* __restrict__ rowend, const float2* __restrict__ cv,
                             const float* __restrict__ b, float* __restrict__ out, int n_rows) {
    int wid  = (blockIdx.x * blockDim.x + threadIdx.x) >> 6;
    int lane = threadIdx.x & 63;
    if (wid >= n_rows) return;
    int beg = (wid == 0) ? 0 : rowend[wid - 1];
    int end = rowend[wid];

    float2 acc = make_float2(0.f, 0.f);
    int j = beg;
    for (; j + 1 < end; j += 2) {   // unroll-2: two gathers in flight
        float2 cv0 = cv[j];          // broadcast (all lanes same addr)
        float2 cv1 = cv[j + 1];
        int c0 = __float_as_int(cv0.x);
        int c1 = __float_as_int(cv1.x);
        float2 v0 = *(reinterpret_cast<const float2*>(b + (size_t)c0 * D_FEAT) + lane);
        float2 v1 = *(reinterpret_cast<const float2*>(b + (size_t)c1 * D_FEAT) + lane);
        acc.x += cv0.y * v0.x;  acc.y += cv0.y * v0.y;
        acc.x += cv1.y * v1.x;  acc.y += cv1.y * v1.y;
    }
    if (j < end) {
        float2 cv0 = cv[j];
        int c0 = __float_as_int(cv0.x);
        float2 v0 = *(reinterpret_cast<const float2*>(b + (size_t)c0 * D_FEAT) + lane);
        acc.x += cv0.y * v0.x;  acc.y += cv0.y * v0.y;
    }
    reinterpret_cast<float2*>(out + (size_t)wid * D_FEAT)[lane] = acc;
}

extern "C" void kernel_launch(void* const* d_in, const int* in_sizes, int n_in,
                              void* d_out, int out_size, void* d_ws, size_t ws_size,
                              hipStream_t stream) {
    const int*   indices = (const int*)d_in[0];     // (2, NNZ) int32
    const float* values  = (const float*)d_in[1];   // (NNZ,)
    const float* b       = (const float*)d_in[3];   // (n_rows, 128)
    float*       out     = (float*)d_out;

    const int nnz    = in_sizes[1];
    const int n_rows = out_size / D_FEAT;
    const int* rowidx = indices;
    const int* colidx = indices + nnz;

    // ws layout: [ rowptr: n_rows ints | pad to 8B | cv: nnz float2 ]
    int*    rowptr = (int*)d_ws;
    size_t  cv_off = ((size_t)n_rows * sizeof(int) + 7) & ~(size_t)7;
    float2* cv     = (float2*)((char*)d_ws + cv_off);

    hipMemsetAsync(rowptr, 0, (size_t)n_rows * sizeof(int), stream);

    const int block = 256;
    hist_kernel<<<2048, block, 0, stream>>>(rowidx, rowptr, nnz);
    scan_kernel<<<1, SCAN_THREADS, 0, stream>>>(rowptr, n_rows);
    scatter_kernel<<<2048, block, 0, stream>>>(rowidx, colidx, values, rowptr, cv, nnz);
    // rowptr now holds END offsets per row.
    rowmm_kernel<<<(n_rows * 64 + block - 1) / block, block, 0, stream>>>(rowptr, cv, b, out, n_rows);
}